// Round 2
// 237.102 us; speedup vs baseline: 1.0114x; 1.0114x over previous
//
#include <hip/hip_runtime.h>

// Causal depthwise conv1d: y[b,s,h] = sum_j x[b, s-(K-1)+j, h] * w[h,j], * mask[b,s]
// B=4, S=4096, H=2048, K=4, fp32. Memory-bound.
//
// R3 history: 2.6 TB/s (41% of copy ceiling) regardless of block shape (R2: 256TPB,
// R3: 512TPB). FETCH_SIZE=78.7MB < x's 134MB => x is ~60% L3-resident across
// dispatches; the y write stream (134MB, zero reuse) thrashes L3 (x+y=268MB > 256MB).
// R4/R5: non-temporal stores for y (evict-first) so x stays fully L3-resident and
// the HBM stream becomes write-dominant. Predicted: FETCH collapses, dur -> ~50-60us.
// R5 fix: __builtin_nontemporal_store needs a native clang vector type, not
// HIP_vector_type<float,4> -> store through ext_vector_type(4) float.

constexpr int B_  = 4;
constexpr int S_  = 4096;
constexpr int H_  = 2048;
constexpr int T_  = 16;          // s-positions per block chunk
constexpr int H4_ = H_ / 4;      // 512 float4 channel-groups per (b,s) row
constexpr int TPB = 512;         // one thread per float4 group -> full row per block

typedef float f32x4 __attribute__((ext_vector_type(4)));  // native vec for nt-store

__global__ __launch_bounds__(TPB) void budgie_dwconv1d_kernel(
    const float* __restrict__ x,     // [B,S,H]
    const float* __restrict__ w,     // [H,K]
    const float* __restrict__ mask,  // [B,S]
    float* __restrict__ y)           // [B,S,H]
{
    const int h4 = threadIdx.x;                      // channel-group id, 0..511
    const int s0 = blockIdx.x * T_;
    const int b  = blockIdx.y;

    const float4* __restrict__ x4 = (const float4*)x;
    const float4* __restrict__ w4 = (const float4*)w;
    f32x4* __restrict__ y4 = (f32x4*)y;

    // Per-channel taps: w[h, 0..3] is contiguous -> one float4 per channel.
    const int hbase = h4 * 4;
    const float4 w0 = w4[hbase + 0];
    const float4 w1 = w4[hbase + 1];
    const float4 w2 = w4[hbase + 2];
    const float4 w3 = w4[hbase + 3];

    const long base = (long)b * S_ * H4_ + h4;       // float4-unit index at s=0

    const float4 zero4 = make_float4(0.f, 0.f, 0.f, 0.f);
    // Preload sliding window x[s0-3], x[s0-2], x[s0-1] (zeros left of s=0).
    float4 xm3 = (s0 >= 3) ? x4[base + (long)(s0 - 3) * H4_] : zero4;
    float4 xm2 = (s0 >= 2) ? x4[base + (long)(s0 - 2) * H4_] : zero4;
    float4 xm1 = (s0 >= 1) ? x4[base + (long)(s0 - 1) * H4_] : zero4;

    #pragma unroll 8
    for (int t = 0; t < T_; ++t) {
        const int s = s0 + t;
        const float4 x0 = x4[base + (long)s * H4_];
        const float  m  = mask[b * S_ + s];

        f32x4 o;
        // channel c: y = x[s-3]*w[c].x + x[s-2]*w[c].y + x[s-1]*w[c].z + x[s]*w[c].w
        o.x = fmaf(xm3.x, w0.x, fmaf(xm2.x, w0.y, fmaf(xm1.x, w0.z, x0.x * w0.w)));
        o.y = fmaf(xm3.y, w1.x, fmaf(xm2.y, w1.y, fmaf(xm1.y, w1.z, x0.y * w1.w)));
        o.z = fmaf(xm3.z, w2.x, fmaf(xm2.z, w2.y, fmaf(xm1.z, w2.z, x0.z * w2.w)));
        o.w = fmaf(xm3.w, w3.x, fmaf(xm2.w, w3.y, fmaf(xm1.w, w3.z, x0.w * w3.w)));
        o.x *= m; o.y *= m; o.z *= m; o.w *= m;

        // Non-temporal: y is write-once/read-never -> evict-first, don't let it
        // thrash x out of the 256MiB Infinity Cache.
        __builtin_nontemporal_store(o, &y4[base + (long)s * H4_]);

        xm3 = xm2; xm2 = xm1; xm1 = x0;
    }
}

extern "C" void kernel_launch(void* const* d_in, const int* in_sizes, int n_in,
                              void* d_out, int out_size, void* d_ws, size_t ws_size,
                              hipStream_t stream) {
    const float* x    = (const float*)d_in[0];   // hidden_states [B,S,H]
    const float* w    = (const float*)d_in[1];   // weight [H,K]
    const float* mask = (const float*)d_in[2];   // attention_mask_2d [B,S]
    float* y = (float*)d_out;

    dim3 grid(S_ / T_, B_);                      // (256, 4) = 1024 blocks
    budgie_dwconv1d_kernel<<<grid, TPB, 0, stream>>>(x, w, mask, y);
}

// Round 3
// 232.710 us; speedup vs baseline: 1.0305x; 1.0189x over previous
//
#include <hip/hip_runtime.h>

// Causal depthwise conv1d: y[b,s,h] = sum_j x[b, s-(K-1)+j, h] * w[h,j], * mask[b,s]
// B=4, S=4096, H=2048, K=4, fp32. Memory-bound.
//
// History: R2(256TPB)/R3(512TPB)/R5(nt-store) all ~2.6 TB/s, 41% of copy ceiling.
// R5 falsified L3-thrash theory (FETCH unchanged; harness fill flushes L3 anyway).
// R6 theory: latency-bound with MLP=1/wave (VGPR=32 => only one x-load in flight)
// and no backfill (1024 blocks = exactly one residency round, occupancy ~50%).
// Fix: depth-4 explicit load ring (4 loads in flight/wave), masks in SGPRs via
// readfirstlane, T_=8 => 2048 blocks = 2 rounds of backfill, launch_bounds(512,8)
// to hold 8 waves/SIMD at VGPR<=64. Predict: BW 2.6 -> >=4.5 TB/s, occ >=70%.

constexpr int B_  = 4;
constexpr int S_  = 4096;
constexpr int H_  = 2048;
constexpr int T_  = 8;           // s-positions per block chunk (was 16)
constexpr int H4_ = H_ / 4;      // 512 float4 channel-groups per (b,s) row
constexpr int TPB = 512;         // one thread per float4 group -> full row per block

typedef float f32x4 __attribute__((ext_vector_type(4)));  // native vec for nt-store

__device__ __forceinline__ float bcast(float v) {
    // block-uniform value -> SGPR (frees a VGPR slot)
    return __uint_as_float(__builtin_amdgcn_readfirstlane(__float_as_uint(v)));
}

__global__ __launch_bounds__(TPB, 8) void budgie_dwconv1d_kernel(
    const float* __restrict__ x,     // [B,S,H]
    const float* __restrict__ w,     // [H,K]
    const float* __restrict__ mask,  // [B,S]
    float* __restrict__ y)           // [B,S,H]
{
    const int h4 = threadIdx.x;                      // channel-group id, 0..511
    const int s0 = blockIdx.x * T_;
    const int b  = blockIdx.y;

    const float4* __restrict__ x4 = (const float4*)x;
    const float4* __restrict__ w4 = (const float4*)w;
    f32x4* __restrict__ y4 = (f32x4*)y;

    // Per-channel taps: w[h, 0..3] is contiguous -> one float4 per channel. 16 VGPR.
    const int hbase = h4 * 4;
    const float4 w0 = w4[hbase + 0];
    const float4 w1 = w4[hbase + 1];
    const float4 w2 = w4[hbase + 2];
    const float4 w3 = w4[hbase + 3];

    const long base = (long)b * S_ * H4_ + h4;       // float4-unit index at s=0

    // Masks for the 8 rows: contiguous 32B, block-uniform -> hoist to SGPRs.
    const float4* mrow = (const float4*)(mask + b * S_ + s0);
    const float4 mA = mrow[0];
    const float4 mB = mrow[1];
    const float mk[T_] = { bcast(mA.x), bcast(mA.y), bcast(mA.z), bcast(mA.w),
                           bcast(mB.x), bcast(mB.y), bcast(mB.z), bcast(mB.w) };

    const float4 zero4 = make_float4(0.f, 0.f, 0.f, 0.f);
    // Sliding window x[s0-3..s0-1] (zeros left of s=0). 12 VGPR.
    float4 xm3 = (s0 >= 3) ? x4[base + (long)(s0 - 3) * H4_] : zero4;
    float4 xm2 = (s0 >= 2) ? x4[base + (long)(s0 - 2) * H4_] : zero4;
    float4 xm1 = (s0 >= 1) ? x4[base + (long)(s0 - 1) * H4_] : zero4;

    // Depth-4 load ring: keep 4 x-loads in flight per wave. 16 VGPR.
    float4 r[4];
    r[0] = x4[base + (long)(s0 + 0) * H4_];
    r[1] = x4[base + (long)(s0 + 1) * H4_];
    r[2] = x4[base + (long)(s0 + 2) * H4_];
    r[3] = x4[base + (long)(s0 + 3) * H4_];

    #pragma unroll
    for (int t = 0; t < T_; ++t) {                   // fully unrolled: static r-indices
        const int s = s0 + t;
        const float4 x0 = r[t & 3];
        if (t + 4 < T_)                              // reissue slot for row s+4
            r[t & 3] = x4[base + (long)(s + 4) * H4_];

        const float m = mk[t];
        f32x4 o;
        o.x = fmaf(xm3.x, w0.x, fmaf(xm2.x, w0.y, fmaf(xm1.x, w0.z, x0.x * w0.w)));
        o.y = fmaf(xm3.y, w1.x, fmaf(xm2.y, w1.y, fmaf(xm1.y, w1.z, x0.y * w1.w)));
        o.z = fmaf(xm3.z, w2.x, fmaf(xm2.z, w2.y, fmaf(xm1.z, w2.z, x0.z * w2.w)));
        o.w = fmaf(xm3.w, w3.x, fmaf(xm2.w, w3.y, fmaf(xm1.w, w3.z, x0.w * w3.w)));
        o.x *= m; o.y *= m; o.z *= m; o.w *= m;

        __builtin_nontemporal_store(o, &y4[base + (long)s * H4_]);

        xm3 = xm2; xm2 = xm1; xm1 = x0;
    }
}

extern "C" void kernel_launch(void* const* d_in, const int* in_sizes, int n_in,
                              void* d_out, int out_size, void* d_ws, size_t ws_size,
                              hipStream_t stream) {
    const float* x    = (const float*)d_in[0];   // hidden_states [B,S,H]
    const float* w    = (const float*)d_in[1];   // weight [H,K]
    const float* mask = (const float*)d_in[2];   // attention_mask_2d [B,S]
    float* y = (float*)d_out;

    dim3 grid(S_ / T_, B_);                      // (512, 4) = 2048 blocks, 2 rounds
    budgie_dwconv1d_kernel<<<grid, TPB, 0, stream>>>(x, w, mask, y);
}